// Round 2
// baseline (1175.464 us; speedup 1.0000x reference)
//
#include <hip/hip_runtime.h>

// MSDformer: deformable conv (q) + transposed-channel attention + proj.
// fp32 throughout (matches reference; CDNA4 has no fp32 MFMA -> vector ALU).
//
// ws layout (floats), total 11,330,304 floats = 45.3 MB:
constexpr int SPLITS = 24;
constexpr size_t OFF_OFS  = 0;                         // [2][18][9216]
constexpr size_t Q_OFS    = 331776;                    // [2][192][9216]
constexpr size_t K_OFS    = Q_OFS + 3538944;
constexpr size_t V_OFS    = K_OFS + 3538944;
constexpr size_t NQ_OFS   = V_OFS + 3538944;           // [2*192] inv-norms
constexpr size_t NK_OFS   = NQ_OFS + 384;
constexpr size_t PART_OFS = NK_OFS + 384;              // [24][12][1024]
constexpr size_t ATTN_OFS = PART_OFS + (size_t)SPLITS * 12 * 1024;  // [12][1024]
constexpr size_t W2_OFS   = ATTN_OFS + 12288;          // [2][192][192]

// ---------------------------------------------------------------- K1: offset conv
// offset[b,o,h,w] = pb[o] + sum_{c,ki,kj} pw[o,c,ki,kj] * x[b,c,h+ki-1,w+kj-1]
// grid 216 = B(2) x o-pairs(9) x h-tiles(12 of 8 rows); block 192 (3 waves).
// Thread owns 2 o-channels x 4 consecutive pixels; weights via wave-uniform
// (scalar) loads; x rows staged in LDS, each LDS read (6 floats) feeds 24 FMA.
__global__ __launch_bounds__(192) void k_offset_conv(
    const float* __restrict__ x, const float* __restrict__ pw,
    const float* __restrict__ pb, float* __restrict__ off)
{
  __shared__ __align__(16) float sx[4 * 10 * 100];   // [ch][row(10)][col pad 100]
  int blk = blockIdx.x;
  int b  = blk / 108;
  int r  = blk % 108;
  int o0 = (r / 12) * 2;
  int h0 = (r % 12) * 8;
  int t  = threadIdx.x;
  int prow = (4 * t) / 96;       // 0..7
  int wb   = (4 * t) % 96;       // multiple of 4
  float acc[2][4] = {};
  for (int c0 = 0; c0 < 192; c0 += 4) {
    __syncthreads();
    for (int e = t; e < 3920; e += 192) {
      int ch = e / 980, r2 = e % 980;
      int row = r2 / 98, col = r2 % 98;
      int gr = h0 + row - 1, gc = col - 1;
      float v = 0.f;
      if (gr >= 0 && gr < 96 && gc >= 0 && gc < 96)
        v = x[((b * 192 + c0 + ch) * 96 + gr) * 96 + gc];
      sx[ch * 1000 + row * 100 + col] = v;
    }
    __syncthreads();
#pragma unroll
    for (int ch = 0; ch < 4; ++ch) {
      float w0[9], w1[9];
#pragma unroll
      for (int kk = 0; kk < 9; ++kk) {   // wave-uniform -> s_load
        w0[kk] = pw[(o0 * 192 + c0 + ch) * 9 + kk];
        w1[kk] = pw[((o0 + 1) * 192 + c0 + ch) * 9 + kk];
      }
#pragma unroll
      for (int ki = 0; ki < 3; ++ki) {
        const float* base = &sx[ch * 1000 + (prow + ki) * 100 + wb];
        float4 f4 = *(const float4*)base;
        float2 f2 = *(const float2*)(base + 4);
        float xv[6] = {f4.x, f4.y, f4.z, f4.w, f2.x, f2.y};
#pragma unroll
        for (int kj = 0; kj < 3; ++kj)
#pragma unroll
          for (int p = 0; p < 4; ++p) {
            acc[0][p] += w0[ki * 3 + kj] * xv[kj + p];
            acc[1][p] += w1[ki * 3 + kj] * xv[kj + p];
          }
      }
    }
  }
  float bb0 = pb[o0], bb1 = pb[o0 + 1];
  int orow = h0 + prow;
  float4 s0 = {acc[0][0] + bb0, acc[0][1] + bb0, acc[0][2] + bb0, acc[0][3] + bb0};
  float4 s1 = {acc[1][0] + bb1, acc[1][1] + bb1, acc[1][2] + bb1, acc[1][3] + bb1};
  *(float4*)&off[((b * 18 + o0) * 96 + orow) * 96 + wb] = s0;
  *(float4*)&off[((b * 18 + o0 + 1) * 96 + orow) * 96 + wb] = s1;
}

// ---------------------------------------------------------------- K2: fused deform conv
// q[b,o,h,w] = sum_{c,n} dw[o,c,n] * bilinear(x_pad; p(b,n,h,w))
// grid 576 = B x H x 3 wtiles(32 px); block 192; thread = 4 o x 8 px (32 acc).
// Bilinear tables built once/block; per 2-channel chunk a 13x44 LDS band is
// staged (reg-prefetched) and x_off gathered from LDS. Slow global-gather path
// only when |offset| > ~5 (prob ~0 but needed for exactness).
__device__ __forceinline__ float deform_slow_sample(
    const float* __restrict__ x, const float* __restrict__ off,
    int b, int c, int n, int h, int w)
{
  int ki = n / 3, kj = n % 3;
  float ox = off[((b * 18 + n) * 96 + h) * 96 + w];
  float oy = off[((b * 18 + 9 + n) * 96 + h) * 96 + w];
  float px = (float)(h + ki) + ox;
  float py = (float)(w + kj) + oy;
  float fx = floorf(px), fy = floorf(py);
  int qx0 = max(0, min(97, (int)fx));
  int qx1 = max(0, min(97, (int)fx + 1));
  int qy0 = max(0, min(97, (int)fy));
  int qy1 = max(0, min(97, (int)fy + 1));
  float pxc = fminf(fmaxf(px, 0.f), 97.f);
  float pyc = fminf(fmaxf(py, 0.f), 97.f);
  float wx0 = 1.f + ((float)qx0 - pxc);
  float wx1 = 1.f - ((float)qx1 - pxc);
  float wy0 = 1.f + ((float)qy0 - pyc);
  float wy1 = 1.f - ((float)qy1 - pyc);
  auto xp = [&](int qx, int qy) -> float {
    int X = qx - 1, Y = qy - 1;
    return (X >= 0 && X < 96 && Y >= 0 && Y < 96)
               ? x[((b * 192 + c) * 96 + X) * 96 + Y] : 0.f;
  };
  return wx0 * wy0 * xp(qx0, qy0) + wx1 * wy1 * xp(qx1, qy1)
       + wx0 * wy1 * xp(qx0, qy1) + wx1 * wy0 * xp(qx1, qy0);
}

__global__ __launch_bounds__(192) void k_deform(
    const float* __restrict__ x, const float* __restrict__ off,
    const float* __restrict__ dw, float* __restrict__ q)
{
  __shared__ __align__(16) float4 tg[288];       // bilinear weights (lt,rb,lb,rt)
  __shared__ unsigned tq[288];                   // packed band-local idx + flag
  __shared__ float band[2 * 13 * 44];            // x band, zero outside image
  __shared__ float Al[192 * 19];                 // dconv_w chunk [o][k] pad 19
  __shared__ __align__(16) float Bl[18 * 32];    // x_off chunk [k][pix]
  int blk = blockIdx.x;
  int b  = blk / 288;
  int r  = blk % 288;
  int h  = r / 3;
  int w0 = (r % 3) * 32;
  int t  = threadIdx.x;

  // phase A: bilinear tables for 32 px x 9 taps
  for (int e = t; e < 288; e += 192) {
    int n = e >> 5, pix = e & 31;
    int ki = n / 3, kj = n % 3;
    int w = w0 + pix;
    float ox = off[((b * 18 + n) * 96 + h) * 96 + w];
    float oy = off[((b * 18 + 9 + n) * 96 + h) * 96 + w];
    float px = (float)(h + ki) + ox;
    float py = (float)(w + kj) + oy;
    float fx = floorf(px), fy = floorf(py);
    int qx0 = max(0, min(97, (int)fx));
    int qx1 = max(0, min(97, (int)fx + 1));
    int qy0 = max(0, min(97, (int)fy));
    int qy1 = max(0, min(97, (int)fy + 1));
    float pxc = fminf(fmaxf(px, 0.f), 97.f);
    float pyc = fminf(fmaxf(py, 0.f), 97.f);
    float wx0 = 1.f + ((float)qx0 - pxc);
    float wx1 = 1.f - ((float)qx1 - pxc);
    float wy0 = 1.f + ((float)qy0 - pyc);
    float wy1 = 1.f - ((float)qy1 - pyc);
    float4 g = {wx0 * wy0, wx1 * wy1, wx0 * wy1, wx1 * wy0};
    int lx0 = qx0 - h + 5, lx1 = qx1 - h + 5;     // image X - (h-6)
    int ly0 = qy0 - w0 + 5, ly1 = qy1 - w0 + 5;
    unsigned flag = (lx0 >= 0 && lx1 < 13 && ly0 >= 0 && ly1 < 44) ? 1u : 0u;
    lx0 = max(0, min(12, lx0)); lx1 = max(0, min(12, lx1));
    ly0 = max(0, min(43, ly0)); ly1 = max(0, min(43, ly1));
    tg[e] = g;
    tq[e] = (unsigned)lx0 | ((unsigned)ly0 << 5) | ((unsigned)lx1 << 11)
          | ((unsigned)ly1 << 16) | (flag << 31);
  }

  // precomputed prefetch addresses (only c0 term changes per chunk)
  int  bbase[6]; bool bval[6];
  int  abase[18];
#pragma unroll
  for (int i = 0; i < 6; ++i) {
    int e = t + i * 192;
    bval[i] = false; bbase[i] = 0;
    if (e < 1144) {
      int cc = e / 572, r2 = e % 572;
      int lx = r2 / 44, ly = r2 % 44;
      int X = h - 6 + lx, Y = w0 - 6 + ly;
      if (X >= 0 && X < 96 && Y >= 0 && Y < 96) {
        bval[i] = true;
        bbase[i] = ((b * 192 + cc) * 96 + X) * 96 + Y;
      }
    }
  }
#pragma unroll
  for (int i = 0; i < 18; ++i) {
    int e = t + i * 192;
    abase[i] = (e / 18) * 1728 + (e % 18);       // dw[o][c0+cc][n] = dw[o*1728+(c0+cc)*9+n]
  }

  float rb[6], ra[18];
#pragma unroll
  for (int i = 0; i < 6; ++i)  rb[i] = bval[i] ? x[bbase[i]] : 0.f;
#pragma unroll
  for (int i = 0; i < 18; ++i) ra[i] = dw[abase[i]];

  int og = t >> 2, pg = t & 3;                    // o = og*4+i, pix = pg*8+j
  float acc[4][8] = {};
  __syncthreads();                                // tables ready

  for (int c0 = 0; c0 < 192; c0 += 2) {
    // commit prefetched regs to LDS
#pragma unroll
    for (int i = 0; i < 6; ++i) { int e = t + i * 192; if (e < 1144) band[e] = rb[i]; }
#pragma unroll
    for (int i = 0; i < 18; ++i) { int e = t + i * 192; Al[(e / 18) * 19 + (e % 18)] = ra[i]; }
    __syncthreads();
    // prefetch next chunk (hidden under B-build + GEMM)
    if (c0 + 2 < 192) {
      int coff = (c0 + 2) * 9216;
#pragma unroll
      for (int i = 0; i < 6; ++i)  rb[i] = bval[i] ? x[bbase[i] + coff] : 0.f;
#pragma unroll
      for (int i = 0; i < 18; ++i) ra[i] = dw[abase[i] + (c0 + 2) * 9];
    }
    // build B = x_off[k=cc*9+n][pix] from LDS band
#pragma unroll
    for (int i = 0; i < 3; ++i) {
      int e = t + i * 192;
      int cc = e / 288, r2 = e % 288;
      int n = r2 >> 5, pix = r2 & 31;
      float4 g = tg[r2];
      unsigned u = tq[r2];
      float val;
      if (u >> 31) {
        int lx0 = u & 31, ly0 = (u >> 5) & 63, lx1 = (u >> 11) & 31, ly1 = (u >> 16) & 63;
        const float* bd = &band[cc * 572];
        val = g.x * bd[lx0 * 44 + ly0] + g.y * bd[lx1 * 44 + ly1]
            + g.z * bd[lx0 * 44 + ly1] + g.w * bd[lx1 * 44 + ly0];
      } else {
        val = deform_slow_sample(x, off, b, c0 + cc, n, h, w0 + pix);
      }
      Bl[(cc * 9 + n) * 32 + pix] = val;
    }
    __syncthreads();
    // GEMM: 18 k-steps, 32 FMA each
    const float4* B4 = (const float4*)Bl;
#pragma unroll
    for (int k = 0; k < 18; ++k) {
      float4 b0 = B4[k * 8 + pg * 2];
      float4 b1 = B4[k * 8 + pg * 2 + 1];
#pragma unroll
      for (int i = 0; i < 4; ++i) {
        float a = Al[(og * 4 + i) * 19 + k];
        acc[i][0] += a * b0.x; acc[i][1] += a * b0.y;
        acc[i][2] += a * b0.z; acc[i][3] += a * b0.w;
        acc[i][4] += a * b1.x; acc[i][5] += a * b1.y;
        acc[i][6] += a * b1.z; acc[i][7] += a * b1.w;
      }
    }
    __syncthreads();
  }
#pragma unroll
  for (int i = 0; i < 4; ++i) {
    int o = og * 4 + i;
    float* dst = &q[(size_t)(b * 192 + o) * 9216 + h * 96 + w0 + pg * 8];
    *(float4*)dst       = {acc[i][0], acc[i][1], acc[i][2], acc[i][3]};
    *(float4*)(dst + 4) = {acc[i][4], acc[i][5], acc[i][6], acc[i][7]};
  }
}

// ---------------------------------------------------------------- K3: k,v GEMM
// [k;v] (384 x 192) @ x (192 x 18432). grid 576 px-tiles; block 256; 6o x 8px.
__global__ __launch_bounds__(256) void k_qkv(
    const float* __restrict__ x, const float* __restrict__ qkvw,
    float* __restrict__ kbuf, float* __restrict__ vbuf)
{
  __shared__ float Al[384 * 17];
  __shared__ __align__(16) float Bl[16 * 32];
  int blk = blockIdx.x;
  int b = blk / 288;
  int pix0 = (blk % 288) * 32;
  int t = threadIdx.x;
  int og = t >> 2, pg = t & 3;
  float acc[6][8] = {};
  for (int c0 = 0; c0 < 192; c0 += 16) {
    __syncthreads();
#pragma unroll
    for (int i = 0; i < 24; ++i) {
      int e = t + i * 256;
      int o = e >> 4, kk = e & 15;
      Al[o * 17 + kk] = qkvw[(size_t)(192 + o) * 192 + c0 + kk];
    }
#pragma unroll
    for (int i = 0; i < 2; ++i) {
      int e = t + i * 256;
      int cc = e >> 5, pix = e & 31;
      Bl[e] = x[(size_t)(b * 192 + c0 + cc) * 9216 + pix0 + pix];
    }
    __syncthreads();
    const float4* B4 = (const float4*)Bl;
#pragma unroll
    for (int k = 0; k < 16; ++k) {
      float4 b0 = B4[k * 8 + pg * 2], b1 = B4[k * 8 + pg * 2 + 1];
#pragma unroll
      for (int i = 0; i < 6; ++i) {
        float a = Al[(og * 6 + i) * 17 + k];
        acc[i][0] += a * b0.x; acc[i][1] += a * b0.y;
        acc[i][2] += a * b0.z; acc[i][3] += a * b0.w;
        acc[i][4] += a * b1.x; acc[i][5] += a * b1.y;
        acc[i][6] += a * b1.z; acc[i][7] += a * b1.w;
      }
    }
  }
#pragma unroll
  for (int i = 0; i < 6; ++i) {
    int o = og * 6 + i;
    float* dst = (o < 192) ? &kbuf[(size_t)(b * 192 + o) * 9216]
                           : &vbuf[(size_t)(b * 192 + o - 192) * 9216];
    dst += pix0 + pg * 8;
    *(float4*)dst       = {acc[i][0], acc[i][1], acc[i][2], acc[i][3]};
    *(float4*)(dst + 4) = {acc[i][4], acc[i][5], acc[i][6], acc[i][7]};
  }
}

// ---------------------------------------------------------------- K4: inv L2 norms per (b,c) row
__global__ __launch_bounds__(256) void k_norms(
    const float* __restrict__ qbuf, const float* __restrict__ kbuf,
    float* __restrict__ nq, float* __restrict__ nk)
{
  __shared__ float red[4];
  int blk = blockIdx.x;
  int which = blk / 384, r = blk % 384;
  const float* src = (which ? kbuf : qbuf) + (size_t)r * 9216;
  int t = threadIdx.x;
  float s = 0.f;
  const float4* s4 = (const float4*)src;
  for (int i = t; i < 2304; i += 256) {
    float4 v = s4[i];
    s += v.x * v.x + v.y * v.y + v.z * v.z + v.w * v.w;
  }
#pragma unroll
  for (int o = 32; o; o >>= 1) s += __shfl_xor(s, o);
  if ((t & 63) == 0) red[t >> 6] = s;
  __syncthreads();
  if (t == 0) {
    float tot = red[0] + red[1] + red[2] + red[3];
    (which ? nk : nq)[r] = 1.f / fmaxf(sqrtf(tot), 1e-12f);
  }
}

// ---------------------------------------------------------------- K5: Gram partials (q_c . k_d)
__global__ __launch_bounds__(256) void k_gram(
    const float* __restrict__ qbuf, const float* __restrict__ kbuf,
    float* __restrict__ part)
{
  __shared__ float sq[32 * 65], sk[32 * 65];
  int blk = blockIdx.x;
  int split = blk / 12, r = blk % 12;
  int b = r / 6, hh = r % 6;
  int n0 = split * 384;
  int t = threadIdx.x;
  int c = t >> 3, dg = t & 7;
  float acc[4] = {};
  for (int sc = 0; sc < 6; ++sc) {
    __syncthreads();
    for (int i = t; i < 2048; i += 256) {
      int cc = i >> 6, j = i & 63;
      size_t g = (size_t)(b * 192 + hh * 32 + cc) * 9216 + n0 + sc * 64 + j;
      sq[cc * 65 + j] = qbuf[g];
      sk[cc * 65 + j] = kbuf[g];
    }
    __syncthreads();
#pragma unroll 8
    for (int j = 0; j < 64; ++j) {
      float qv = sq[c * 65 + j];
#pragma unroll
      for (int i2 = 0; i2 < 4; ++i2)
        acc[i2] += qv * sk[(dg * 4 + i2) * 65 + j];
    }
  }
  float* dst = &part[((size_t)split * 12 + b * 6 + hh) * 1024 + c * 32 + dg * 4];
  *(float4*)dst = {acc[0], acc[1], acc[2], acc[3]};
}

// ---------------------------------------------------------------- K6: reduce + scale + softmax(d)
__global__ __launch_bounds__(1024) void k_softmax(
    const float* __restrict__ part, const float* __restrict__ nq,
    const float* __restrict__ nk, const float* __restrict__ temp,
    float* __restrict__ attn)
{
  int bi = blockIdx.x;            // b*6+h
  int b = bi / 6, h = bi % 6;
  int t = threadIdx.x;
  int c = t >> 5, d = t & 31;
  float val = 0.f;
  for (int s = 0; s < SPLITS; ++s) val += part[((size_t)s * 12 + bi) * 1024 + t];
  val *= nq[b * 192 + h * 32 + c] * nk[b * 192 + h * 32 + d] * temp[h];
  float m = val;
#pragma unroll
  for (int o = 16; o; o >>= 1) m = fmaxf(m, __shfl_xor(m, o));
  float e = expf(val - m);
  float s = e;
#pragma unroll
  for (int o = 16; o; o >>= 1) s += __shfl_xor(s, o);
  attn[(size_t)bi * 1024 + t] = e / s;
}

// ---------------------------------------------------------------- K7: W2[b] = proj_w . blockdiag(attn)
// W2[b][o][h*32+d] = sum_ci proj[o][h*32+ci] * attn[b][h][ci][d]
__global__ __launch_bounds__(256) void k_w2(
    const float* __restrict__ attn, const float* __restrict__ projw,
    float* __restrict__ w2)
{
  __shared__ float sa[32 * 33];
  int bi = blockIdx.x;            // b*6+h
  int b = bi / 6, h = bi % 6;
  int t = threadIdx.x;
  for (int i = t; i < 1024; i += 256)
    sa[(i >> 5) * 33 + (i & 31)] = attn[(size_t)bi * 1024 + i];
  __syncthreads();
  for (int e = t; e < 6144; e += 256) {
    int o = e >> 5, d = e & 31;
    float s = 0.f;
#pragma unroll 8
    for (int ci = 0; ci < 32; ++ci)
      s += projw[o * 192 + h * 32 + ci] * sa[ci * 33 + d];
    w2[((size_t)b * 192 + o) * 192 + h * 32 + d] = s;
  }
}

// ---------------------------------------------------------------- K8: out = W2[b] @ v (fused attn.v + proj)
__global__ __launch_bounds__(256) void k_out(
    const float* __restrict__ vbuf, const float* __restrict__ w2,
    float* __restrict__ out)
{
  __shared__ float Al[192 * 17];
  __shared__ __align__(16) float Bl[16 * 32];
  int blk = blockIdx.x;
  int b = blk / 288;
  int pix0 = (blk % 288) * 32;
  int t = threadIdx.x;
  int og = t >> 2, pg = t & 3;
  float acc[3][8] = {};
  for (int c0 = 0; c0 < 192; c0 += 16) {
    __syncthreads();
#pragma unroll
    for (int i = 0; i < 12; ++i) {
      int e = t + i * 256;
      int o = e >> 4, kk = e & 15;
      Al[o * 17 + kk] = w2[((size_t)b * 192 + o) * 192 + c0 + kk];
    }
#pragma unroll
    for (int i = 0; i < 2; ++i) {
      int e = t + i * 256;
      int cc = e >> 5, pix = e & 31;
      Bl[e] = vbuf[(size_t)(b * 192 + c0 + cc) * 9216 + pix0 + pix];
    }
    __syncthreads();
    const float4* B4 = (const float4*)Bl;
#pragma unroll
    for (int k = 0; k < 16; ++k) {
      float4 b0 = B4[k * 8 + pg * 2], b1 = B4[k * 8 + pg * 2 + 1];
#pragma unroll
      for (int i = 0; i < 3; ++i) {
        float a = Al[(og * 3 + i) * 17 + k];
        acc[i][0] += a * b0.x; acc[i][1] += a * b0.y;
        acc[i][2] += a * b0.z; acc[i][3] += a * b0.w;
        acc[i][4] += a * b1.x; acc[i][5] += a * b1.y;
        acc[i][6] += a * b1.z; acc[i][7] += a * b1.w;
      }
    }
  }
#pragma unroll
  for (int i = 0; i < 3; ++i) {
    int o = og * 3 + i;
    float* dst = &out[(size_t)(b * 192 + o) * 9216 + pix0 + pg * 8];
    *(float4*)dst       = {acc[i][0], acc[i][1], acc[i][2], acc[i][3]};
    *(float4*)(dst + 4) = {acc[i][4], acc[i][5], acc[i][6], acc[i][7]};
  }
}

// ----------------------------------------------------------------
extern "C" void kernel_launch(void* const* d_in, const int* in_sizes, int n_in,
                              void* d_out, int out_size, void* d_ws, size_t ws_size,
                              hipStream_t stream) {
  (void)in_sizes; (void)n_in; (void)out_size; (void)ws_size;
  const float* x     = (const float*)d_in[0];
  const float* pw    = (const float*)d_in[1];
  const float* pb    = (const float*)d_in[2];
  const float* dw    = (const float*)d_in[3];
  const float* qkvw  = (const float*)d_in[4];
  const float* projw = (const float*)d_in[5];
  const float* temp  = (const float*)d_in[6];
  float* ws   = (float*)d_ws;
  float* off  = ws + OFF_OFS;
  float* qb   = ws + Q_OFS;
  float* kb   = ws + K_OFS;
  float* vb   = ws + V_OFS;
  float* nq   = ws + NQ_OFS;
  float* nk   = ws + NK_OFS;
  float* part = ws + PART_OFS;
  float* attn = ws + ATTN_OFS;
  float* w2   = ws + W2_OFS;
  float* out  = (float*)d_out;

  k_offset_conv<<<dim3(216), dim3(192), 0, stream>>>(x, pw, pb, off);
  k_qkv        <<<dim3(576), dim3(256), 0, stream>>>(x, qkvw, kb, vb);
  k_deform     <<<dim3(576), dim3(192), 0, stream>>>(x, off, dw, qb);
  k_norms      <<<dim3(768), dim3(256), 0, stream>>>(qb, kb, nq, nk);
  k_gram       <<<dim3(288), dim3(256), 0, stream>>>(qb, kb, part);
  k_softmax    <<<dim3(12),  dim3(1024),0, stream>>>(part, nq, nk, temp, attn);
  k_w2         <<<dim3(12),  dim3(256), 0, stream>>>(attn, projw, w2);
  k_out        <<<dim3(576), dim3(256), 0, stream>>>(vb, w2, out);
}